// Round 5
// baseline (3591.574 us; speedup 1.0000x reference)
//
#include <hip/hip_runtime.h>
#include <hip/hip_bf16.h>
#include <math.h>

// ---------------------------------------------------------------------------
// MLA prefill. Round 5: split-bf16 MFMA GEMMs with ON-THE-FLY hi/lo split
// (fp32 in -> fp32 out, no cast arenas). Workspace = 161.5 MB (round-1 layout).
// Attention stays audited fp32 VALU kernel.
// ---------------------------------------------------------------------------

#define T_TOK   4096
#define SEQ_LEN 2048
#define NB      2
#define NHEAD   16
#define DMODEL  2048
#define DCQ     1536
#define DCKV    512
#define DROPE   64
#define QHD     192
#define MEGD    256

typedef unsigned short u16;
typedef unsigned int   u32;
typedef __attribute__((ext_vector_type(8))) short short8v;
typedef __attribute__((ext_vector_type(4))) float f32x4;

__device__ __forceinline__ u16 f2bf(float f) {
    u32 u = __float_as_uint(f);
    u32 r = u + 0x7FFFu + ((u >> 16) & 1u);   // RNE
    return (u16)(r >> 16);
}
__device__ __forceinline__ float bf2f(u16 h) {
    return __uint_as_float(((u32)h) << 16);
}

// ----------------------- split-bf16 MFMA GEMM -------------------------------
// C[m][n] = sum_k A[m][k]*W[n][k]; A,W fp32 in global; split to (hi,lo) bf16
// during LDS staging; C ~= Ah*Wh + Ah*Wl + Al*Wh (drop Al*Wl; rel err ~8e-6).
// 64x64 tile, BK=32, 256 thr = 4 waves, each wave a 32x32 quadrant
// (2x2 fragments of 16x16x32). Verified layouts (learn_hip m89/m91/m97):
//   A/B frag: elem j of lane l = M[row16 + (l&15)][(l>>4)*8 + j]
//   C/D:      col = l&15, row = 4*(l>>4) + reg
__global__ __launch_bounds__(256) void gemm_split_nt(
    const float* __restrict__ A, int lda,
    const float* __restrict__ W, int ldw,
    float* __restrict__ C, int ldc, int K)
{
    __shared__ __align__(16) u16 Ahs[64][32];
    __shared__ __align__(16) u16 Als[64][32];
    __shared__ __align__(16) u16 Whs[64][32];
    __shared__ __align__(16) u16 Wls[64][32];

    const int tid  = threadIdx.x;
    const int wave = tid >> 6;
    const int lane = tid & 63;
    const int wr = (wave >> 1) * 32;     // wave row offset in 64x64 tile
    const int wc = (wave & 1) * 32;      // wave col offset
    const int m0 = blockIdx.y * 64;
    const int n0 = blockIdx.x * 64;

    const int srow = tid >> 2;           // staging row: 0..63
    const int scol = (tid & 3) * 8;      // staging col: 0,8,16,24

    f32x4 acc[2][2];
    #pragma unroll
    for (int i = 0; i < 2; ++i)
        #pragma unroll
        for (int j = 0; j < 2; ++j)
            acc[i][j] = (f32x4){0.f, 0.f, 0.f, 0.f};

    const float* Ap = A + (size_t)(m0 + srow) * lda + scol;
    const float* Wp = W + (size_t)(n0 + srow) * ldw + scol;

    const int fr = lane & 15;            // fragment row within 16
    const int kg = (lane >> 4) * 8;      // k-group start

    for (int k0 = 0; k0 < K; k0 += 32) {
        float av[8], wv[8];
        *(float4*)&av[0] = *(const float4*)(Ap + k0);
        *(float4*)&av[4] = *(const float4*)(Ap + k0 + 4);
        *(float4*)&wv[0] = *(const float4*)(Wp + k0);
        *(float4*)&wv[4] = *(const float4*)(Wp + k0 + 4);
        short8v ah, al, wh, wl;
        #pragma unroll
        for (int j = 0; j < 8; ++j) {
            u16 hb = f2bf(av[j]);
            ah[j] = (short)hb;
            al[j] = (short)f2bf(av[j] - bf2f(hb));
            u16 hw = f2bf(wv[j]);
            wh[j] = (short)hw;
            wl[j] = (short)f2bf(wv[j] - bf2f(hw));
        }
        __syncthreads();   // prev iter's fragment reads done
        *(short8v*)&Ahs[srow][scol] = ah;
        *(short8v*)&Als[srow][scol] = al;
        *(short8v*)&Whs[srow][scol] = wh;
        *(short8v*)&Wls[srow][scol] = wl;
        __syncthreads();

        short8v afh[2], afl[2], wfh[2], wfl[2];
        #pragma unroll
        for (int i = 0; i < 2; ++i) {
            afh[i] = *(const short8v*)&Ahs[wr + i * 16 + fr][kg];
            afl[i] = *(const short8v*)&Als[wr + i * 16 + fr][kg];
            wfh[i] = *(const short8v*)&Whs[wc + i * 16 + fr][kg];
            wfl[i] = *(const short8v*)&Wls[wc + i * 16 + fr][kg];
        }
        #pragma unroll
        for (int i = 0; i < 2; ++i)
            #pragma unroll
            for (int j = 0; j < 2; ++j) {
                acc[i][j] = __builtin_amdgcn_mfma_f32_16x16x32_bf16(afh[i], wfh[j], acc[i][j], 0, 0, 0);
                acc[i][j] = __builtin_amdgcn_mfma_f32_16x16x32_bf16(afh[i], wfl[j], acc[i][j], 0, 0, 0);
                acc[i][j] = __builtin_amdgcn_mfma_f32_16x16x32_bf16(afl[i], wfh[j], acc[i][j], 0, 0, 0);
            }
    }

    const int rq = (lane >> 4) * 4;
    #pragma unroll
    for (int i = 0; i < 2; ++i)
        #pragma unroll
        for (int j = 0; j < 2; ++j)
            #pragma unroll
            for (int r = 0; r < 4; ++r)
                C[(size_t)(m0 + wr + i * 16 + rq + r) * ldc + (n0 + wc + j * 16 + fr)]
                    = acc[i][j][r];
}

// ------------------------------ RMSNorm ------------------------------------
// One block (256 thr) per row; width = NPT*256 exactly; in-place; then *w.
template <int NPT>
__global__ __launch_bounds__(256) void rmsnorm_kernel(
    float* __restrict__ data, int stride, const float* __restrict__ w, int width)
{
    const int row = blockIdx.x;
    float* p = data + (size_t)row * stride;
    const int tid = threadIdx.x;

    float v[NPT];
    float ss = 0.f;
    #pragma unroll
    for (int i = 0; i < NPT; ++i) { v[i] = p[tid + i * 256]; ss += v[i] * v[i]; }
    #pragma unroll
    for (int off = 32; off; off >>= 1) ss += __shfl_xor(ss, off, 64);

    __shared__ float red[4];
    if ((tid & 63) == 0) red[tid >> 6] = ss;
    __syncthreads();
    ss = red[0] + red[1] + red[2] + red[3];

    const float scale = rsqrtf(ss / (float)width + 1e-7f);
    #pragma unroll
    for (int i = 0; i < NPT; ++i)
        p[tid + i * 256] = w[tid + i * 256] * (v[i] * scale);
}

// -------------------------------- RoPE -------------------------------------
// reference: de-interleave (even->first half, odd->second), then
// out[j]    = v[2j]*cos_j   - v[2j+1]*sin_j          (j < 32)
// out[32+j] = v[2j+1]*cos_j + v[2j]*sin_j
__device__ __forceinline__ void rope_row(const float* __restrict__ vin,
                                         float* __restrict__ vout, float p)
{
    float buf[64];
    #pragma unroll
    for (int j = 0; j < 64; ++j) buf[j] = vin[j];
    #pragma unroll
    for (int j = 0; j < 32; ++j) {
        float f = powf(10000.f, -(float)j * (1.f / 32.f));
        float a = p * f;
        float c = cosf(a), s = sinf(a);
        vout[j]      = buf[2 * j] * c - buf[2 * j + 1] * s;
        vout[32 + j] = buf[2 * j + 1] * c + buf[2 * j] * s;
    }
}

__global__ __launch_bounds__(256) void rope_q_kernel(float* __restrict__ q,
                                                     const int* __restrict__ pos)
{
    const int idx = blockIdx.x * 256 + threadIdx.x;
    if (idx >= T_TOK * NHEAD) return;
    const int t = idx >> 4, h = idx & 15;
    float* v = q + (size_t)t * (NHEAD * QHD) + h * QHD + 128;
    rope_row(v, v, (float)pos[t]);
}

__global__ __launch_bounds__(256) void rope_k_kernel(const float* __restrict__ ckv,
                                                     const int* __restrict__ pos,
                                                     float* __restrict__ kr)
{
    const int t = blockIdx.x * 256 + threadIdx.x;
    if (t >= T_TOK) return;
    rope_row(ckv + (size_t)t * (DCKV + DROPE) + DCKV, kr + (size_t)t * DROPE,
             (float)pos[t]);
}

// ---------------------------- Flash attention ------------------------------
// BQ=BKT=32. 128 threads: row = tid>>2 (0..31), sub = tid&3.
// Each lane: score cols {c8*4+sub}, d_v chunk {dd*4+sub}.
// K and V time-share one LDS region (K as [c][196], V as [d][36] transposed).
#define BQ  32
#define BKT 32
#define KSTR 196   // K row stride (196%32==4 -> conflict-free col reads)
#define VSTR 36    // V row stride

__global__ __launch_bounds__(128) void mla_attn_kernel(
    const float* __restrict__ q,    // [T, 3072] (rope already applied)
    const float* __restrict__ kv,   // [T, 4096]
    const float* __restrict__ kr,   // [T, 64]
    float* __restrict__ o)          // [T, 2048]
{
    const int qt = blockIdx.x;
    const int h  = blockIdx.y;
    const int b  = blockIdx.z;
    const int q0 = qt * BQ;
    const int tid = threadIdx.x;
    const int row = tid >> 2;
    const int sub = tid & 3;

    __shared__ __align__(16) float Qs[BQ][KSTR];
    __shared__ __align__(16) float KVs[BKT * KSTR];  // K view / V view (transposed)
    __shared__ __align__(16) float Ps[BQ][VSTR];

    // stage Q tile (rows q0..q0+31), dims sub*48..sub*48+47
    {
        const float* src = q + (size_t)(b * SEQ_LEN + q0 + row) * (NHEAD * QHD)
                             + h * QHD + sub * 48;
        #pragma unroll
        for (int i = 0; i < 12; ++i)
            *(float4*)&Qs[row][sub * 48 + i * 4] = *(const float4*)(src + i * 4);
    }

    float m = -1e30f, l = 0.f;
    float acc[32];
    #pragma unroll
    for (int i = 0; i < 32; ++i) acc[i] = 0.f;

    const float scale = 0.07216878364870323f;  // 1/sqrt(192)
    const int ntile = qt + 1;

    for (int kt = 0; kt < ntile; ++kt) {
        const int k0 = kt * BKT;
        const int tk = b * SEQ_LEN + k0 + row;   // this thread's K/V row
        __syncthreads();   // prev PV done with V region
        // stage K[c=row][dims sub*48..+47]  (nope from kv, rope from kr)
        #pragma unroll
        for (int i = 0; i < 12; ++i) {
            int d = sub * 48 + i * 4;
            float4 v;
            if (d < 128) v = *(const float4*)(kv + (size_t)tk * (NHEAD * MEGD) + h * MEGD + d);
            else         v = *(const float4*)(kr + (size_t)tk * DROPE + (d - 128));
            *(float4*)&KVs[row * KSTR + d] = v;
        }
        __syncthreads();
        // scores: 8 cols per lane over 192 dims
        float sc[8];
        #pragma unroll
        for (int i = 0; i < 8; ++i) sc[i] = 0.f;
        for (int d0 = 0; d0 < 192; d0 += 4) {
            float4 qv = *(const float4*)&Qs[row][d0];
            #pragma unroll
            for (int c8 = 0; c8 < 8; ++c8) {
                float4 kk = *(const float4*)&KVs[(c8 * 4 + sub) * KSTR + d0];
                sc[c8] += qv.x * kk.x + qv.y * kk.y + qv.z * kk.z + qv.w * kk.w;
            }
        }
        // mask + online softmax (4-lane groups per row)
        const int qglob = q0 + row;
        float mt = -1e30f;
        #pragma unroll
        for (int c8 = 0; c8 < 8; ++c8) {
            int kg = k0 + c8 * 4 + sub;
            sc[c8] = (kg <= qglob) ? sc[c8] * scale : -1e30f;
            mt = fmaxf(mt, sc[c8]);
        }
        mt = fmaxf(mt, __shfl_xor(mt, 1, 64));
        mt = fmaxf(mt, __shfl_xor(mt, 2, 64));
        const float mnew = fmaxf(m, mt);
        const float alpha = __expf(m - mnew);
        float psum = 0.f;
        #pragma unroll
        for (int c8 = 0; c8 < 8; ++c8) {
            float pv = (sc[c8] > -1e29f) ? __expf(sc[c8] - mnew) : 0.f;
            Ps[row][c8 * 4 + sub] = pv;
            psum += pv;
        }
        psum += __shfl_xor(psum, 1, 64);
        psum += __shfl_xor(psum, 2, 64);
        l = l * alpha + psum;
        m = mnew;
        #pragma unroll
        for (int i = 0; i < 32; ++i) acc[i] *= alpha;
        __syncthreads();   // scores done reading K region; Ps visible soon
        // stage V transposed: V[d][c] at KVs[d*VSTR + c]; this thread: c=row,
        // dims sub*32..+31
        #pragma unroll
        for (int i = 0; i < 8; ++i) {
            int d = sub * 32 + i * 4;
            float4 v = *(const float4*)(kv + (size_t)tk * (NHEAD * MEGD) + h * MEGD + 128 + d);
            KVs[(d + 0) * VSTR + row] = v.x;
            KVs[(d + 1) * VSTR + row] = v.y;
            KVs[(d + 2) * VSTR + row] = v.z;
            KVs[(d + 3) * VSTR + row] = v.w;
        }
        __syncthreads();   // V staged, Ps visible
        // PV: probs to regs, then acc[dd] (d = dd*4+sub)
        float p[32];
        #pragma unroll
        for (int i = 0; i < 8; ++i) {
            float4 v = *(const float4*)&Ps[row][i * 4];
            p[i * 4 + 0] = v.x; p[i * 4 + 1] = v.y;
            p[i * 4 + 2] = v.z; p[i * 4 + 3] = v.w;
        }
        #pragma unroll
        for (int dd = 0; dd < 32; ++dd) {
            const int d = dd * 4 + sub;
            const float4* vrow = (const float4*)&KVs[d * VSTR];
            float s = 0.f;
            #pragma unroll
            for (int c4 = 0; c4 < 8; ++c4) {
                float4 vv = vrow[c4];
                s += p[c4 * 4 + 0] * vv.x + p[c4 * 4 + 1] * vv.y
                   + p[c4 * 4 + 2] * vv.z + p[c4 * 4 + 3] * vv.w;
            }
            acc[dd] += s;
        }
    }

    const float inv_l = 1.f / l;
    float* dst = o + (size_t)(b * SEQ_LEN + q0 + row) * (NHEAD * 128) + h * 128;
    #pragma unroll
    for (int dd = 0; dd < 32; ++dd) dst[dd * 4 + sub] = acc[dd] * inv_l;
}

// ------------------------------- launcher ----------------------------------
extern "C" void kernel_launch(void* const* d_in, const int* in_sizes, int n_in,
                              void* d_out, int out_size, void* d_ws, size_t ws_size,
                              hipStream_t stream)
{
    const float* x         = (const float*)d_in[0];
    const int*   pos       = (const int*)d_in[1];
    const float* w_q_down  = (const float*)d_in[2];
    const float* q_norm_w  = (const float*)d_in[3];
    const float* w_q_up    = (const float*)d_in[4];
    const float* w_kv_down = (const float*)d_in[5];
    const float* kv_norm_w = (const float*)d_in[6];
    const float* w_kv_up   = (const float*)d_in[7];
    const float* w_out     = (const float*)d_in[8];
    float* out = (float*)d_out;

    float* ws = (float*)d_ws;
    // ao (attn out, 4096x2048) aliases q_dn (4096x1536): q_dn dead before
    // attention writes ao. slot0 sized for the wider (2048) view.
    float* ao   = ws;
    float* q_dn = ws;
    float* ckv  = ws + (size_t)T_TOK * 2048;
    float* q_up = ckv + (size_t)T_TOK * (DCKV + DROPE);
    float* kvb  = q_up + (size_t)T_TOK * (NHEAD * QHD);
    float* kr   = kvb + (size_t)T_TOK * (NHEAD * MEGD);
    // total: 4096*(2048+576+3072+4096+64)*4B = 161.5 MB

    dim3 blk(256);
    // q_down: [T,2048]@[1536,2048]^T
    gemm_split_nt<<<dim3(DCQ / 64, T_TOK / 64), blk, 0, stream>>>(
        x, DMODEL, w_q_down, DMODEL, q_dn, DCQ, DMODEL);
    // kv_down: [T,2048]@[576,2048]^T
    gemm_split_nt<<<dim3((DCKV + DROPE) / 64, T_TOK / 64), blk, 0, stream>>>(
        x, DMODEL, w_kv_down, DMODEL, ckv, DCKV + DROPE, DMODEL);
    // norms (in place)
    rmsnorm_kernel<6><<<T_TOK, 256, 0, stream>>>(q_dn, DCQ, q_norm_w, DCQ);
    rmsnorm_kernel<2><<<T_TOK, 256, 0, stream>>>(ckv, DCKV + DROPE, kv_norm_w, DCKV);
    // k rope (reads raw ckv[512:576] - untouched by norm)
    rope_k_kernel<<<T_TOK / 256, 256, 0, stream>>>(ckv, pos, kr);
    // q_up: [T,1536]@[3072,1536]^T
    gemm_split_nt<<<dim3((NHEAD * QHD) / 64, T_TOK / 64), blk, 0, stream>>>(
        q_dn, DCQ, w_q_up, DCQ, q_up, NHEAD * QHD, DCQ);
    // kv_up: [T,512(stride 576)]@[4096,512]^T
    gemm_split_nt<<<dim3((NHEAD * MEGD) / 64, T_TOK / 64), blk, 0, stream>>>(
        ckv, DCKV + DROPE, w_kv_up, DCKV, kvb, NHEAD * MEGD, DCKV);
    // q rope (in place on q_up)
    rope_q_kernel<<<(T_TOK * NHEAD) / 256, 256, 0, stream>>>(q_up, pos);
    // attention
    mla_attn_kernel<<<dim3(SEQ_LEN / BQ, NHEAD, NB), dim3(128), 0, stream>>>(
        q_up, kvb, kr, ao);
    // out projection: [T,2048]@[2048,2048]^T
    gemm_split_nt<<<dim3(DMODEL / 64, T_TOK / 64), blk, 0, stream>>>(
        ao, DMODEL, w_out, DMODEL, out, DMODEL, DMODEL);
}

// Round 6
// 1399.523 us; speedup vs baseline: 2.5663x; 2.5663x over previous
//
#include <hip/hip_runtime.h>
#include <hip/hip_bf16.h>
#include <math.h>

// ---------------------------------------------------------------------------
// MLA prefill. Round 6: attention -> split-bf16 MFMA flash kernel.
// GEMMs unchanged (split-bf16 MFMA, on-the-fly split). Workspace 161.5 MB.
// ---------------------------------------------------------------------------

#define T_TOK   4096
#define SEQ_LEN 2048
#define NB      2
#define NHEAD   16
#define DMODEL  2048
#define DCQ     1536
#define DCKV    512
#define DROPE   64
#define QHD     192
#define MEGD    256

typedef unsigned short u16;
typedef unsigned int   u32;
typedef __attribute__((ext_vector_type(8))) short short8v;
typedef __attribute__((ext_vector_type(4))) float f32x4;

__device__ __forceinline__ u16 f2bf(float f) {
    u32 u = __float_as_uint(f);
    u32 r = u + 0x7FFFu + ((u >> 16) & 1u);   // RNE
    return (u16)(r >> 16);
}
__device__ __forceinline__ float bf2f(u16 h) {
    return __uint_as_float(((u32)h) << 16);
}

// ----------------------- split-bf16 MFMA GEMM -------------------------------
// C[m][n] = sum_k A[m][k]*W[n][k]; on-the-fly (hi,lo) split during staging;
// C ~= Ah*Wh + Ah*Wl + Al*Wh. 64x64 tile, BK=32, 4 waves = 2x2 quadrants.
__global__ __launch_bounds__(256) void gemm_split_nt(
    const float* __restrict__ A, int lda,
    const float* __restrict__ W, int ldw,
    float* __restrict__ C, int ldc, int K)
{
    __shared__ __align__(16) u16 Ahs[64][32];
    __shared__ __align__(16) u16 Als[64][32];
    __shared__ __align__(16) u16 Whs[64][32];
    __shared__ __align__(16) u16 Wls[64][32];

    const int tid  = threadIdx.x;
    const int wave = tid >> 6;
    const int lane = tid & 63;
    const int wr = (wave >> 1) * 32;
    const int wc = (wave & 1) * 32;
    const int m0 = blockIdx.y * 64;
    const int n0 = blockIdx.x * 64;

    const int srow = tid >> 2;
    const int scol = (tid & 3) * 8;

    f32x4 acc[2][2];
    #pragma unroll
    for (int i = 0; i < 2; ++i)
        #pragma unroll
        for (int j = 0; j < 2; ++j)
            acc[i][j] = (f32x4){0.f, 0.f, 0.f, 0.f};

    const float* Ap = A + (size_t)(m0 + srow) * lda + scol;
    const float* Wp = W + (size_t)(n0 + srow) * ldw + scol;

    const int fr = lane & 15;
    const int kg = (lane >> 4) * 8;

    for (int k0 = 0; k0 < K; k0 += 32) {
        float av[8], wv[8];
        *(float4*)&av[0] = *(const float4*)(Ap + k0);
        *(float4*)&av[4] = *(const float4*)(Ap + k0 + 4);
        *(float4*)&wv[0] = *(const float4*)(Wp + k0);
        *(float4*)&wv[4] = *(const float4*)(Wp + k0 + 4);
        short8v ah, al, wh, wl;
        #pragma unroll
        for (int j = 0; j < 8; ++j) {
            u16 hb = f2bf(av[j]);
            ah[j] = (short)hb;
            al[j] = (short)f2bf(av[j] - bf2f(hb));
            u16 hw = f2bf(wv[j]);
            wh[j] = (short)hw;
            wl[j] = (short)f2bf(wv[j] - bf2f(hw));
        }
        __syncthreads();
        *(short8v*)&Ahs[srow][scol] = ah;
        *(short8v*)&Als[srow][scol] = al;
        *(short8v*)&Whs[srow][scol] = wh;
        *(short8v*)&Wls[srow][scol] = wl;
        __syncthreads();

        short8v afh[2], afl[2], wfh[2], wfl[2];
        #pragma unroll
        for (int i = 0; i < 2; ++i) {
            afh[i] = *(const short8v*)&Ahs[wr + i * 16 + fr][kg];
            afl[i] = *(const short8v*)&Als[wr + i * 16 + fr][kg];
            wfh[i] = *(const short8v*)&Whs[wc + i * 16 + fr][kg];
            wfl[i] = *(const short8v*)&Wls[wc + i * 16 + fr][kg];
        }
        #pragma unroll
        for (int i = 0; i < 2; ++i)
            #pragma unroll
            for (int j = 0; j < 2; ++j) {
                acc[i][j] = __builtin_amdgcn_mfma_f32_16x16x32_bf16(afh[i], wfh[j], acc[i][j], 0, 0, 0);
                acc[i][j] = __builtin_amdgcn_mfma_f32_16x16x32_bf16(afh[i], wfl[j], acc[i][j], 0, 0, 0);
                acc[i][j] = __builtin_amdgcn_mfma_f32_16x16x32_bf16(afl[i], wfh[j], acc[i][j], 0, 0, 0);
            }
    }

    const int rq = (lane >> 4) * 4;
    #pragma unroll
    for (int i = 0; i < 2; ++i)
        #pragma unroll
        for (int j = 0; j < 2; ++j)
            #pragma unroll
            for (int r = 0; r < 4; ++r)
                C[(size_t)(m0 + wr + i * 16 + rq + r) * ldc + (n0 + wc + j * 16 + fr)]
                    = acc[i][j][r];
}

// ------------------------------ RMSNorm ------------------------------------
template <int NPT>
__global__ __launch_bounds__(256) void rmsnorm_kernel(
    float* __restrict__ data, int stride, const float* __restrict__ w, int width)
{
    const int row = blockIdx.x;
    float* p = data + (size_t)row * stride;
    const int tid = threadIdx.x;

    float v[NPT];
    float ss = 0.f;
    #pragma unroll
    for (int i = 0; i < NPT; ++i) { v[i] = p[tid + i * 256]; ss += v[i] * v[i]; }
    #pragma unroll
    for (int off = 32; off; off >>= 1) ss += __shfl_xor(ss, off, 64);

    __shared__ float red[4];
    if ((tid & 63) == 0) red[tid >> 6] = ss;
    __syncthreads();
    ss = red[0] + red[1] + red[2] + red[3];

    const float scale = rsqrtf(ss / (float)width + 1e-7f);
    #pragma unroll
    for (int i = 0; i < NPT; ++i)
        p[tid + i * 256] = w[tid + i * 256] * (v[i] * scale);
}

// -------------------------------- RoPE -------------------------------------
__device__ __forceinline__ void rope_row(const float* __restrict__ vin,
                                         float* __restrict__ vout, float p)
{
    float buf[64];
    #pragma unroll
    for (int j = 0; j < 64; ++j) buf[j] = vin[j];
    #pragma unroll
    for (int j = 0; j < 32; ++j) {
        float f = powf(10000.f, -(float)j * (1.f / 32.f));
        float a = p * f;
        float c = cosf(a), s = sinf(a);
        vout[j]      = buf[2 * j] * c - buf[2 * j + 1] * s;
        vout[32 + j] = buf[2 * j + 1] * c + buf[2 * j] * s;
    }
}

__global__ __launch_bounds__(256) void rope_q_kernel(float* __restrict__ q,
                                                     const int* __restrict__ pos)
{
    const int idx = blockIdx.x * 256 + threadIdx.x;
    if (idx >= T_TOK * NHEAD) return;
    const int t = idx >> 4, h = idx & 15;
    float* v = q + (size_t)t * (NHEAD * QHD) + h * QHD + 128;
    rope_row(v, v, (float)pos[t]);
}

__global__ __launch_bounds__(256) void rope_k_kernel(const float* __restrict__ ckv,
                                                     const int* __restrict__ pos,
                                                     float* __restrict__ kr)
{
    const int t = blockIdx.x * 256 + threadIdx.x;
    if (t >= T_TOK) return;
    rope_row(ckv + (size_t)t * (DCKV + DROPE) + DCKV, kr + (size_t)t * DROPE,
             (float)pos[t]);
}

// ---------------------- MFMA flash attention (split-bf16) -------------------
// BQ=64 q-rows/block, BKT=32 k/tile, 256 thr = 4 waves; wave w owns rows
// [w*16, w*16+16). Q hi/lo fragments in registers. K [32][200], Vt [128][40],
// P per-wave [16][40] in LDS (all u16 hi/lo pairs). Scores & PV each use the
// 3-product split (AhBh + AhBl + AlBh) -> fp32-grade accuracy.
// Verified MFMA layouts (same as gemm_split_nt, passed R5):
//   A/B frag: lane l elem j = M[l&15][(l>>4)*8 + j]
//   C/D:      col = l&15, row = 4*(l>>4) + reg
#define BQA   64
#define BKA   32
#define KSTR2 200
#define VSTR2 40
#define PSTR2 40

__global__ __launch_bounds__(256) void mla_attn_mfma(
    const float* __restrict__ q,    // [T, 3072] (rope applied)
    const float* __restrict__ kv,   // [T, 4096]
    const float* __restrict__ kr,   // [T, 64]
    float* __restrict__ o)          // [T, 2048]
{
    __shared__ __align__(16) u16 KhS[BKA][KSTR2];
    __shared__ __align__(16) u16 KlS[BKA][KSTR2];
    __shared__ __align__(16) u16 VhS[128][VSTR2];
    __shared__ __align__(16) u16 VlS[128][VSTR2];
    __shared__ __align__(16) u16 PhS[4][16][PSTR2];
    __shared__ __align__(16) u16 PlS[4][16][PSTR2];

    const int qt = (int)(gridDim.x - 1) - (int)blockIdx.x;  // heavy blocks first
    const int h  = blockIdx.y;
    const int b  = blockIdx.z;
    const int q0 = qt * BQA;
    const int tid  = threadIdx.x;
    const int wave = tid >> 6;
    const int lane = tid & 63;
    const int fr = lane & 15;
    const int gp = lane >> 4;        // 0..3
    const int kg = gp * 8;           // fragment k-offset

    // ---- Q fragments (rows q0 + wave*16 + fr), split hi/lo in registers
    short8v qh[6], ql[6];
    {
        const float* qrow = q + (size_t)(b * SEQ_LEN + q0 + wave * 16 + fr) * (NHEAD * QHD)
                              + h * QHD;
        #pragma unroll
        for (int ks = 0; ks < 6; ++ks) {
            float v8[8];
            *(float4*)&v8[0] = *(const float4*)(qrow + ks * 32 + kg);
            *(float4*)&v8[4] = *(const float4*)(qrow + ks * 32 + kg + 4);
            #pragma unroll
            for (int j = 0; j < 8; ++j) {
                u16 hb = f2bf(v8[j]);
                qh[ks][j] = (short)hb;
                ql[ks][j] = (short)f2bf(v8[j] - bf2f(hb));
            }
        }
    }

    f32x4 acc_o[8];
    #pragma unroll
    for (int i = 0; i < 8; ++i) acc_o[i] = (f32x4){0.f, 0.f, 0.f, 0.f};
    float mrow[4] = {-1e30f, -1e30f, -1e30f, -1e30f};
    float lrow[4] = {0.f, 0.f, 0.f, 0.f};

    const float scale = 0.07216878364870323f;  // 1/sqrt(192)
    const int ntile = 2 * qt + 2;
    const int qmax_w = q0 + 16 * wave + 15;    // last row this wave owns

    for (int kt = 0; kt < ntile; ++kt) {
        const int k0 = kt * BKA;
        __syncthreads();   // prev tile's LDS reads complete

        // ---- stage K[32][192] hi/lo: thread: row tid>>3, cols (tid&7)*24..+23
        {
            const int krow = tid >> 3;
            const int c0 = (tid & 7) * 24;
            const int tk = b * SEQ_LEN + k0 + krow;
            float v24[24];
            #pragma unroll
            for (int i = 0; i < 6; ++i) {
                const int d = c0 + i * 4;
                float4 vv = (d < 128)
                    ? *(const float4*)(kv + (size_t)tk * (NHEAD * MEGD) + h * MEGD + d)
                    : *(const float4*)(kr + (size_t)tk * DROPE + (d - 128));
                *(float4*)&v24[i * 4] = vv;
            }
            #pragma unroll
            for (int i = 0; i < 6; ++i) {
                ushort4 hh, ll;
                u16* hp = &hh.x; u16* lp = &ll.x;
                #pragma unroll
                for (int j = 0; j < 4; ++j) {
                    float f = v24[i * 4 + j];
                    u16 hb = f2bf(f);
                    hp[j] = hb;
                    lp[j] = f2bf(f - bf2f(hb));
                }
                *(ushort4*)&KhS[krow][c0 + i * 4] = hh;
                *(ushort4*)&KlS[krow][c0 + i * 4] = ll;
            }
        }
        // ---- stage V transposed [128 d][32 k] hi/lo via 4x4 micro-transpose
        {
            const int kq = (tid & 7) * 4;     // k quad base
            const int dq = (tid >> 3) * 4;    // d quad base
            float4 vv[4];
            #pragma unroll
            for (int r = 0; r < 4; ++r) {
                const int tk = b * SEQ_LEN + k0 + kq + r;
                vv[r] = *(const float4*)(kv + (size_t)tk * (NHEAD * MEGD) + h * MEGD + 128 + dq);
            }
            const float* vp = (const float*)&vv[0];
            #pragma unroll
            for (int i = 0; i < 4; ++i) {     // d offset
                ushort4 hh, ll;
                u16* hp = &hh.x; u16* lp = &ll.x;
                #pragma unroll
                for (int r = 0; r < 4; ++r) { // k offset
                    float f = vp[r * 4 + i];
                    u16 hb = f2bf(f);
                    hp[r] = hb;
                    lp[r] = f2bf(f - bf2f(hb));
                }
                *(ushort4*)&VhS[dq + i][kq] = hh;
                *(ushort4*)&VlS[dq + i][kq] = ll;
            }
        }
        __syncthreads();   // tiles staged

        if (k0 <= qmax_w) {   // causal: this wave still needs this tile
            // ---- scores: S[16][32] = Q(16x192) . K^T, split 3-product
            f32x4 s0 = (f32x4){0.f, 0.f, 0.f, 0.f};
            f32x4 s1 = (f32x4){0.f, 0.f, 0.f, 0.f};
            #pragma unroll
            for (int ks = 0; ks < 6; ++ks) {
                short8v kh0 = *(const short8v*)&KhS[fr][ks * 32 + kg];
                short8v kl0 = *(const short8v*)&KlS[fr][ks * 32 + kg];
                short8v kh1 = *(const short8v*)&KhS[fr + 16][ks * 32 + kg];
                short8v kl1 = *(const short8v*)&KlS[fr + 16][ks * 32 + kg];
                s0 = __builtin_amdgcn_mfma_f32_16x16x32_bf16(qh[ks], kh0, s0, 0, 0, 0);
                s0 = __builtin_amdgcn_mfma_f32_16x16x32_bf16(qh[ks], kl0, s0, 0, 0, 0);
                s0 = __builtin_amdgcn_mfma_f32_16x16x32_bf16(ql[ks], kh0, s0, 0, 0, 0);
                s1 = __builtin_amdgcn_mfma_f32_16x16x32_bf16(qh[ks], kh1, s1, 0, 0, 0);
                s1 = __builtin_amdgcn_mfma_f32_16x16x32_bf16(qh[ks], kl1, s1, 0, 0, 0);
                s1 = __builtin_amdgcn_mfma_f32_16x16x32_bf16(ql[ks], kh1, s1, 0, 0, 0);
            }
            // ---- mask + online softmax (rows 4*gp+r, cols fr / fr+16)
            float alpha[4];
            #pragma unroll
            for (int r = 0; r < 4; ++r) {
                const int qglob = q0 + wave * 16 + 4 * gp + r;
                float sc0 = (k0 + fr      <= qglob) ? s0[r] * scale : -1e30f;
                float sc1 = (k0 + 16 + fr <= qglob) ? s1[r] * scale : -1e30f;
                float mt = fmaxf(sc0, sc1);
                mt = fmaxf(mt, __shfl_xor(mt, 1, 64));
                mt = fmaxf(mt, __shfl_xor(mt, 2, 64));
                mt = fmaxf(mt, __shfl_xor(mt, 4, 64));
                mt = fmaxf(mt, __shfl_xor(mt, 8, 64));
                const float mnew = fmaxf(mrow[r], mt);
                alpha[r] = __expf(mrow[r] - mnew);
                const float p0 = __expf(sc0 - mnew);
                const float p1 = __expf(sc1 - mnew);
                float ps = p0 + p1;
                ps += __shfl_xor(ps, 1, 64);
                ps += __shfl_xor(ps, 2, 64);
                ps += __shfl_xor(ps, 4, 64);
                ps += __shfl_xor(ps, 8, 64);
                lrow[r] = lrow[r] * alpha[r] + ps;
                mrow[r] = mnew;
                // P -> LDS (hi/lo), wave-local region
                u16 h0 = f2bf(p0);
                PhS[wave][4 * gp + r][fr]      = h0;
                PlS[wave][4 * gp + r][fr]      = f2bf(p0 - bf2f(h0));
                u16 h1 = f2bf(p1);
                PhS[wave][4 * gp + r][fr + 16] = h1;
                PlS[wave][4 * gp + r][fr + 16] = f2bf(p1 - bf2f(h1));
            }
            // rescale O
            #pragma unroll
            for (int f2 = 0; f2 < 8; ++f2)
                #pragma unroll
                for (int r = 0; r < 4; ++r)
                    acc_o[f2][r] *= alpha[r];
            // ---- PV: O[16][128] += P(16x32) . V(32x128)
            short8v ph = *(const short8v*)&PhS[wave][fr][kg];
            short8v pl = *(const short8v*)&PlS[wave][fr][kg];
            #pragma unroll
            for (int f2 = 0; f2 < 8; ++f2) {
                short8v vh = *(const short8v*)&VhS[fr + 16 * f2][kg];
                short8v vl = *(const short8v*)&VlS[fr + 16 * f2][kg];
                acc_o[f2] = __builtin_amdgcn_mfma_f32_16x16x32_bf16(ph, vh, acc_o[f2], 0, 0, 0);
                acc_o[f2] = __builtin_amdgcn_mfma_f32_16x16x32_bf16(ph, vl, acc_o[f2], 0, 0, 0);
                acc_o[f2] = __builtin_amdgcn_mfma_f32_16x16x32_bf16(pl, vh, acc_o[f2], 0, 0, 0);
            }
        }
    }

    // ---- epilogue
    float inv[4];
    #pragma unroll
    for (int r = 0; r < 4; ++r) inv[r] = 1.f / lrow[r];
    #pragma unroll
    for (int r = 0; r < 4; ++r) {
        const size_t t = (size_t)(b * SEQ_LEN + q0 + wave * 16 + 4 * gp + r);
        float* dst = o + t * (NHEAD * 128) + h * 128 + fr;
        #pragma unroll
        for (int f2 = 0; f2 < 8; ++f2)
            dst[16 * f2] = acc_o[f2][r] * inv[r];
    }
}

// ------------------------------- launcher ----------------------------------
extern "C" void kernel_launch(void* const* d_in, const int* in_sizes, int n_in,
                              void* d_out, int out_size, void* d_ws, size_t ws_size,
                              hipStream_t stream)
{
    const float* x         = (const float*)d_in[0];
    const int*   pos       = (const int*)d_in[1];
    const float* w_q_down  = (const float*)d_in[2];
    const float* q_norm_w  = (const float*)d_in[3];
    const float* w_q_up    = (const float*)d_in[4];
    const float* w_kv_down = (const float*)d_in[5];
    const float* kv_norm_w = (const float*)d_in[6];
    const float* w_kv_up   = (const float*)d_in[7];
    const float* w_out     = (const float*)d_in[8];
    float* out = (float*)d_out;

    float* ws = (float*)d_ws;
    // ao (attn out, 4096x2048) aliases q_dn (4096x1536): q_dn dead before
    // attention writes ao. slot0 sized for the wider (2048) view.
    float* ao   = ws;
    float* q_dn = ws;
    float* ckv  = ws + (size_t)T_TOK * 2048;
    float* q_up = ckv + (size_t)T_TOK * (DCKV + DROPE);
    float* kvb  = q_up + (size_t)T_TOK * (NHEAD * QHD);
    float* kr   = kvb + (size_t)T_TOK * (NHEAD * MEGD);
    // total: 4096*(2048+576+3072+4096+64)*4B = 161.5 MB

    dim3 blk(256);
    gemm_split_nt<<<dim3(DCQ / 64, T_TOK / 64), blk, 0, stream>>>(
        x, DMODEL, w_q_down, DMODEL, q_dn, DCQ, DMODEL);
    gemm_split_nt<<<dim3((DCKV + DROPE) / 64, T_TOK / 64), blk, 0, stream>>>(
        x, DMODEL, w_kv_down, DMODEL, ckv, DCKV + DROPE, DMODEL);
    rmsnorm_kernel<6><<<T_TOK, 256, 0, stream>>>(q_dn, DCQ, q_norm_w, DCQ);
    rmsnorm_kernel<2><<<T_TOK, 256, 0, stream>>>(ckv, DCKV + DROPE, kv_norm_w, DCKV);
    rope_k_kernel<<<T_TOK / 256, 256, 0, stream>>>(ckv, pos, kr);
    gemm_split_nt<<<dim3((NHEAD * QHD) / 64, T_TOK / 64), blk, 0, stream>>>(
        q_dn, DCQ, w_q_up, DCQ, q_up, NHEAD * QHD, DCQ);
    gemm_split_nt<<<dim3((NHEAD * MEGD) / 64, T_TOK / 64), blk, 0, stream>>>(
        ckv, DCKV + DROPE, w_kv_up, DCKV, kvb, NHEAD * MEGD, DCKV);
    rope_q_kernel<<<(T_TOK * NHEAD) / 256, 256, 0, stream>>>(q_up, pos);
    // MFMA attention: grid (S/64, H, B)
    mla_attn_mfma<<<dim3(SEQ_LEN / BQA, NHEAD, NB), dim3(256), 0, stream>>>(
        q_up, kvb, kr, ao);
    gemm_split_nt<<<dim3(DMODEL / 64, T_TOK / 64), blk, 0, stream>>>(
        ao, DMODEL, w_out, DMODEL, out, DMODEL, DMODEL);
}